// Round 10
// baseline (94.956 us; speedup 1.0000x reference)
//
#include <hip/hip_runtime.h>

// FlowNetC correlation, B=8 C=256 H=64 W=128, 9x9 grid.
// out[b,dy*9+dx,h,w] = (1/256) * sum_c in1[b,c,h,w]*in2[b,c,h+dy-4,w+dx-4]
// (in2 zero-padded by 4 in h,w).
//
// Block = (b,h,dy) -> ONE in2 row. 4608 blocks x 256 thr (4 waves).
// Thread = (q:16 w-octs) x (cslo:4); wave w owns channels 16p+4w+cslo.
// Wave-private staging, no barriers in main loop; counted vmcnt(4).
// R10 = R9 + overwrite-race fix: lgkmcnt(0)+sched_barrier after each COMPUTE
// before re-STAGING that buffer. R9 lesson: COMPUTE's ds_reads vs next
// STAGE's DMA-write to the same buffer was only timing-safe; 6 reads x 12
// waves (~860cyc queued LDS) exceeded DMA return latency -> corruption.
// The fence makes ordering architectural at ~zero cost (FMA deps already
// force those waits).
// R9 experiment (still live): all VMEM dense 16-line/KB -> tests whether the
// CU vmem path is line-request-rate limited (R8: 10->4 instrs was flat).
// R4-R8 lessons: (256,3) is the spill-free point; WRITE_SIZE==20736KB is
// the spill tripwire.

#define AS1 __attribute__((address_space(1)))
#define AS3 __attribute__((address_space(3)))

namespace {

constexpr int Cc = 256, Hh = 64, Ww = 128;
constexpr int HW = Hh * Ww;   // 8192
constexpr int ND = 81;
constexpr int PBUF = 1040;    // per wave/buffer: 520 in2 (512+4zero+pad) + 512 v1 + 8 pad
constexpr int WREG = 2 * PBUF;  // 2080 floats per wave (double-buffered)

__device__ __forceinline__ void async16(const float* g, float* l) {
  __builtin_amdgcn_global_load_lds((const AS1 unsigned int*)g,
                                   (AS3 unsigned int*)l, 16, 0, 0);
}

__global__ __launch_bounds__(256, 3) void corr_kernel(
    const float* __restrict__ in1, const float* __restrict__ in2,
    float* __restrict__ out) {
  __shared__ __align__(16) float lds[8320];  // 4 waves x 2080; reduce reuses [0,4608)

  const int tid = threadIdx.x;
  const int w = tid >> 6;
  const int lane = tid & 63;
  const int q = lane & 15;
  const int cslo = lane >> 4;

  // XCD swizzle: dispatch i -> XCD i%8; XCD x gets batch x; 9 dy-siblings of
  // one (b,h) are consecutive -> co-resident on one XCD, sharing rows in L2.
  const int bid0 = blockIdx.x;
  const int nb = (bid0 & 7) * 576 + (bid0 >> 3);
  const int b = nb / 576;
  const int rem = nb - b * 576;
  const int h = rem / 9;
  const int dy = rem - h * 9;
  const int row2 = h + dy - 4;

  float* outbase = out + (((size_t)b * ND + (size_t)dy * 9) * Hh + h) * Ww;

  if ((unsigned)row2 >= (unsigned)Hh) {  // dy shifts row out of range -> zeros
    if (tid < 144) {
      const int dx = tid >> 4, qq = tid & 15;
      const float4 z = make_float4(0.f, 0.f, 0.f, 0.f);
      *(float4*)(outbase + (size_t)dx * HW + 8 * qq) = z;
      *(float4*)(outbase + (size_t)dx * HW + 8 * qq + 4) = z;
    }
    return;
  }

  const int wb = w * WREG;
  // zero the 16-B zero-slot of each phase buffer (floats 512..515)
  if (lane < 8) lds[wb + (lane >> 2) * PBUF + 512 + (lane & 3)] = 0.0f;

  // ---- in2 staging source mapping (inverse of the [odds|evens]+rot layout) ----
  // dest slot s (16B units) in [0,128): c = s>>5, v = s&31, vp = (v-2c)&31,
  // quad g = vp<16 ? 2*vp+1 : 2*(vp-16). instr k covers slots 64k + lane.
  int srcA, srcB;
  {
    const int s0 = lane, c0 = s0 >> 5, v0 = s0 & 31;
    const int vp0 = (v0 - 2 * c0) & 31;
    const int g0 = (vp0 < 16) ? (2 * vp0 + 1) : (2 * (vp0 - 16));
    srcA = (4 * w + c0) * HW + 4 * g0;
    const int s1 = 64 + lane, c1 = s1 >> 5, v1_ = s1 & 31;
    const int vp1 = (v1_ - 2 * c1) & 31;
    const int g1 = (vp1 < 16) ? (2 * vp1 + 1) : (2 * (vp1 - 16));
    srcB = (4 * w + c1) * HW + 4 * g1;
  }
  // ---- v1 staging source mapping (dense, linear) ----
  // instr k: lane l -> dest float 520 + 256k + 4l ; holds ch (4w + 2k + (l>>5)),
  // x = (4l)&127.
  const int v1srcA = (4 * w + (lane >> 5)) * HW + ((4 * lane) & 127);
  const int v1srcB = (4 * w + 2 + (lane >> 5)) * HW + ((4 * lane) & 127);

  // ---- per-thread in2 window read offsets (floats, within phase buffer) ----
  // window t[k] = x 8q-4+k; quads {q-1, 16+q, q, 17+q} rotated by 2*cslo;
  // q==0 first / q==15 last quad -> zero slot (float 512).
  const int ro0 = (q == 0) ? 512 : (cslo * 32 + ((q - 1 + 2 * cslo) & 31)) * 4;
  const int ro1 = (cslo * 32 + ((16 + q + 2 * cslo) & 31)) * 4;
  const int ro2 = (cslo * 32 + ((q + 2 * cslo) & 31)) * 4;
  const int ro3 = (q == 15) ? 512 : (cslo * 32 + ((17 + q + 2 * cslo) & 31)) * 4;
  // v1 read offset: floats 520 + cslo*128 + 8q (2x b128)
  const int vro = 520 + cslo * 128 + 8 * q;

  const float* in2row = in2 + ((size_t)b * Cc * Hh + row2) * Ww;
  const float* in1row = in1 + ((size_t)b * Cc * Hh + h) * Ww;

#define STAGE(P, BI)                                                   \
  {                                                                    \
    const float* s2_ = in2row + (size_t)(16 * (P)) * HW;               \
    const float* s1_ = in1row + (size_t)(16 * (P)) * HW;               \
    async16(s2_ + srcA, &lds[wb + (BI) * PBUF]);                       \
    async16(s2_ + srcB, &lds[wb + (BI) * PBUF + 256]);                 \
    async16(s1_ + v1srcA, &lds[wb + (BI) * PBUF + 520]);               \
    async16(s1_ + v1srcB, &lds[wb + (BI) * PBUF + 776]);               \
  }

#define COMPUTE(BI)                                                      \
  {                                                                      \
    const int bb_ = wb + (BI) * PBUF;                                    \
    const float4 A_ = *(const float4*)&lds[bb_ + ro0]; /* t0..3  */      \
    const float4 B_ = *(const float4*)&lds[bb_ + ro1]; /* t4..7  */      \
    const float4 C_ = *(const float4*)&lds[bb_ + ro2]; /* t8..11 */      \
    const float4 D_ = *(const float4*)&lds[bb_ + ro3]; /* t12..15*/      \
    const float4 Va_ = *(const float4*)&lds[bb_ + vro];                  \
    const float4 Vb_ = *(const float4*)&lds[bb_ + vro + 4];              \
    const float t_[16] = {A_.x, A_.y, A_.z, A_.w, B_.x, B_.y, B_.z, B_.w,\
                          C_.x, C_.y, C_.z, C_.w, D_.x, D_.y, D_.z, D_.w};\
    const float v_[8] = {Va_.x, Va_.y, Va_.z, Va_.w,                     \
                         Vb_.x, Vb_.y, Vb_.z, Vb_.w};                    \
    _Pragma("unroll") for (int dx_ = 0; dx_ < 9; ++dx_)                  \
      _Pragma("unroll") for (int px_ = 0; px_ < 8; ++px_)                \
        acc[px_][dx_] = fmaf(v_[px_], t_[px_ + dx_], acc[px_][dx_]);     \
  }

#define VMCNT(N) asm volatile("s_waitcnt vmcnt(" #N ")" ::: "memory")
// Read-retire fence: all ds_reads of the preceding COMPUTE have returned
// before the next STAGE may overwrite that buffer (HW DMA writes are not
// ordered vs queued ds_reads). sched_barrier pins codegen (rule #18).
#define LGKM0                                             \
  asm volatile("s_waitcnt lgkmcnt(0)" ::: "memory");      \
  __builtin_amdgcn_sched_barrier(0)

  float acc[8][9];
#pragma unroll
  for (int px = 0; px < 8; ++px)
#pragma unroll
    for (int dx = 0; dx < 9; ++dx) acc[px][dx] = 0.0f;

  STAGE(0, 0);

#pragma unroll 1
  for (int pp = 0; pp < 16; pp += 2) {
    STAGE(pp + 1, 1);
    VMCNT(4);  // drain phase pp's 4 ops; keep pp+1's 4 in flight
    COMPUTE(0);
    LGKM0;     // buf0 reads retired before re-staging buf0
    if (pp + 2 < 16) {
      STAGE(pp + 2, 0);
      VMCNT(4);
    } else {
      VMCNT(0);
    }
    COMPUTE(1);
    LGKM0;     // buf1 reads retired before next iteration re-stages buf1
  }

  // reduce the 4 cslo slices within each wave (lanes q, q+16, q+32, q+48)
#pragma unroll
  for (int px = 0; px < 8; ++px)
#pragma unroll
    for (int dx = 0; dx < 9; ++dx) {
      float v = acc[px][dx];
      v += __shfl_xor(v, 16, 64);
      v += __shfl_xor(v, 32, 64);
      acc[px][dx] = v;
    }

  __syncthreads();  // all waves done with staging region before overwrite
  if (cslo == 0) {  // wave partial: lds[((w*16+q)*9+dx)*8+px]
    const int pb = (w * 16 + q) * 72;
#pragma unroll
    for (int dx = 0; dx < 9; ++dx) {
      *(float4*)&lds[pb + dx * 8] =
          make_float4(acc[0][dx], acc[1][dx], acc[2][dx], acc[3][dx]);
      *(float4*)&lds[pb + dx * 8 + 4] =
          make_float4(acc[4][dx], acc[5][dx], acc[6][dx], acc[7][dx]);
    }
  }
  __syncthreads();

  if (tid < 144) {  // sum 4 wave-partials, scale, store
    const int dx = tid >> 4, qq = tid & 15;
    const float s = 1.0f / 256.0f;
    float r[8];
#pragma unroll
    for (int px = 0; px < 8; ++px) r[px] = 0.0f;
#pragma unroll
    for (int w4 = 0; w4 < 4; ++w4) {
      const int pb = ((w4 * 16 + qq) * 9 + dx) * 8;
      const float4 lo = *(const float4*)&lds[pb];
      const float4 hi = *(const float4*)&lds[pb + 4];
      r[0] += lo.x; r[1] += lo.y; r[2] += lo.z; r[3] += lo.w;
      r[4] += hi.x; r[5] += hi.y; r[6] += hi.z; r[7] += hi.w;
    }
    *(float4*)(outbase + (size_t)dx * HW + 8 * qq) =
        make_float4(r[0] * s, r[1] * s, r[2] * s, r[3] * s);
    *(float4*)(outbase + (size_t)dx * HW + 8 * qq + 4) =
        make_float4(r[4] * s, r[5] * s, r[6] * s, r[7] * s);
  }
}

}  // namespace

extern "C" void kernel_launch(void* const* d_in, const int* in_sizes, int n_in,
                              void* d_out, int out_size, void* d_ws,
                              size_t ws_size, hipStream_t stream) {
  (void)in_sizes; (void)n_in; (void)out_size; (void)d_ws; (void)ws_size;
  const float* in1 = (const float*)d_in[0];
  const float* in2 = (const float*)d_in[1];
  float* outp = (float*)d_out;
  corr_kernel<<<4608, 256, 0, stream>>>(in1, in2, outp);
}